// Round 1
// baseline (4293.147 us; speedup 1.0000x reference)
//
#include <hip/hip_runtime.h>
#include <math.h>

#define T_   2048
#define DIN  512
#define H_   384
#define H4_  1536
#define C_   8
#define BT_  16384

// ---------------------------------------------------------------------------
// Weight transposes (run once per launch; tiny)
// ---------------------------------------------------------------------------

// enc_w [H][DIN][7] -> ewt [kap = k*512+i][H]  (K-tiles of 16 stay within one tap)
__global__ void k_transpose_encw(const float* __restrict__ in, float* __restrict__ out) {
    int idx = blockIdx.x * 256 + threadIdx.x;
    if (idx >= 3584 * H_) return;
    int o = idx % H_;
    int kap = idx / H_;
    int i = kap & 511;
    int k = kap >> 9;
    out[idx] = in[o * 3584 + i * 7 + k];
}

// batched 2D transpose: in [batch][rows][cols] -> out [batch][cols][rows]
__global__ void k_transpose_b(const float* __restrict__ in, float* __restrict__ out,
                              int rows, int cols) {
    long total = (long)rows * cols;
    long idx = (long)blockIdx.x * 256 + threadIdx.x;
    if (idx >= total) return;
    const float* ib = in + (long)blockIdx.y * total;
    float* ob = out + (long)blockIdx.y * total;
    int c = (int)(idx / rows);   // out row
    int r = (int)(idx % rows);   // out col
    ob[idx] = ib[(long)r * cols + c];
}

// ---------------------------------------------------------------------------
// Row-wise LayerNorm over H=384, one wave per row
// ---------------------------------------------------------------------------
__global__ void k_ln(const float* __restrict__ in, float* __restrict__ out,
                     const float* __restrict__ g, const float* __restrict__ b) {
    int row = blockIdx.x;
    int lane = threadIdx.x;
    const float* ir = in + (long)row * H_;
    float v[6];
    float s = 0.f;
#pragma unroll
    for (int j = 0; j < 6; ++j) { v[j] = ir[lane + (j << 6)]; s += v[j]; }
#pragma unroll
    for (int o = 32; o > 0; o >>= 1) s += __shfl_down(s, o, 64);
    s = __shfl(s, 0, 64);
    float mean = s * (1.f / 384.f);
    float q = 0.f;
#pragma unroll
    for (int j = 0; j < 6; ++j) { float d = v[j] - mean; q += d * d; }
#pragma unroll
    for (int o = 32; o > 0; o >>= 1) q += __shfl_down(q, o, 64);
    q = __shfl(q, 0, 64);
    float rstd = rsqrtf(q * (1.f / 384.f) + 1e-5f);
    float* orow = out + (long)row * H_;
#pragma unroll
    for (int j = 0; j < 6; ++j) {
        int c = lane + (j << 6);
        orow[c] = (v[j] - mean) * rstd * g[c] + b[c];
    }
}

// ---------------------------------------------------------------------------
// Fused depthwise conv (k=7, pad=3, along t) + LayerNorm, one wave per (b,t) row
// h layout: [B][T][H]
// ---------------------------------------------------------------------------
__global__ void k_dwconv_ln(const float* __restrict__ h, float* __restrict__ out,
                            const float* __restrict__ w, const float* __restrict__ wb,
                            const float* __restrict__ g, const float* __restrict__ gb) {
    int row = blockIdx.x;
    int b = row >> 11;
    int t = row & 2047;
    int lane = threadIdx.x;
    const float* hb = h + ((long)b * T_) * H_;
    float v[6];
    float s = 0.f;
#pragma unroll
    for (int j = 0; j < 6; ++j) {
        int c = lane + (j << 6);
        float acc = wb[c];
        const float* wc = w + c * 7;
#pragma unroll
        for (int k = 0; k < 7; ++k) {
            int tt = t + k - 3;
            if ((unsigned)tt < (unsigned)T_)
                acc = fmaf(hb[(long)tt * H_ + c], wc[k], acc);
        }
        v[j] = acc;
        s += acc;
    }
#pragma unroll
    for (int o = 32; o > 0; o >>= 1) s += __shfl_down(s, o, 64);
    s = __shfl(s, 0, 64);
    float mean = s * (1.f / 384.f);
    float q = 0.f;
#pragma unroll
    for (int j = 0; j < 6; ++j) { float d = v[j] - mean; q += d * d; }
#pragma unroll
    for (int o = 32; o > 0; o >>= 1) q += __shfl_down(q, o, 64);
    q = __shfl(q, 0, 64);
    float rstd = rsqrtf(q * (1.f / 384.f) + 1e-5f);
    float* orow = out + (long)row * H_;
#pragma unroll
    for (int j = 0; j < 6; ++j) {
        int c = lane + (j << 6);
        orow[c] = (v[j] - mean) * rstd * g[c] + gb[c];
    }
}

// ---------------------------------------------------------------------------
// fp32 tiled GEMM: C[M,N] = A[M,K] @ B[K,N] + bias (+gelu | +res)
// 128x128 tile, BK=16, 256 threads, 8x8 accum/thread (2x2 blocks of 4x4 at +-64)
// MODE 0: +bias    MODE 1: +bias, exact GELU    MODE 2: +bias, +res
// ---------------------------------------------------------------------------
__device__ __forceinline__ float gelu_exact(float x) {
    return 0.5f * x * (1.0f + erff(x * 0.70710678118654752f));
}

template <int MODE>
__global__ __launch_bounds__(256) void k_gemm(
    const float* __restrict__ A, const float* __restrict__ Bm,
    const float* __restrict__ bias, const float* res, float* Cm, int N, int Kd) {
    __shared__ float As[16][132];
    __shared__ float Bs[16][136];
    const int tid = threadIdx.x;
    const int tx = tid & 15, ty = tid >> 4;
    const int m0 = blockIdx.y << 7, n0 = blockIdx.x << 7;
    const int arow = tid >> 2;
    const int akq = (tid & 3) << 2;
    const int brow = tid >> 4;
    const int bnq = (tid & 15) << 2;
    float acc[2][2][4][4] = {};
    const float* Ap0 = A + (long)(m0 + arow) * Kd + akq;
    const float* Ap1 = Ap0 + (long)64 * Kd;
    const float* Bp = Bm + (long)brow * N + n0 + bnq;

    for (int k0 = 0; k0 < Kd; k0 += 16) {
        float4 a0 = *(const float4*)(Ap0 + k0);
        float4 a1 = *(const float4*)(Ap1 + k0);
        float4 b0 = *(const float4*)(Bp + (long)k0 * N);
        float4 b1 = *(const float4*)(Bp + (long)k0 * N + 64);
        __syncthreads();
        As[akq + 0][arow] = a0.x;  As[akq + 1][arow] = a0.y;
        As[akq + 2][arow] = a0.z;  As[akq + 3][arow] = a0.w;
        As[akq + 0][arow + 64] = a1.x;  As[akq + 1][arow + 64] = a1.y;
        As[akq + 2][arow + 64] = a1.z;  As[akq + 3][arow + 64] = a1.w;
        *(float4*)&Bs[brow][bnq] = b0;
        *(float4*)&Bs[brow][bnq + 64] = b1;
        __syncthreads();
#pragma unroll
        for (int k = 0; k < 16; ++k) {
            float4 av0 = *(const float4*)&As[k][ty << 2];
            float4 av1 = *(const float4*)&As[k][(ty << 2) + 64];
            float4 bv0 = *(const float4*)&Bs[k][tx << 2];
            float4 bv1 = *(const float4*)&Bs[k][(tx << 2) + 64];
            float a_[8] = {av0.x, av0.y, av0.z, av0.w, av1.x, av1.y, av1.z, av1.w};
            float b_[8] = {bv0.x, bv0.y, bv0.z, bv0.w, bv1.x, bv1.y, bv1.z, bv1.w};
#pragma unroll
            for (int im = 0; im < 2; ++im)
#pragma unroll
                for (int r2 = 0; r2 < 4; ++r2)
#pragma unroll
                    for (int in2 = 0; in2 < 2; ++in2)
#pragma unroll
                        for (int c2 = 0; c2 < 4; ++c2)
                            acc[im][in2][r2][c2] =
                                fmaf(a_[im * 4 + r2], b_[in2 * 4 + c2], acc[im][in2][r2][c2]);
        }
    }

#pragma unroll
    for (int im = 0; im < 2; ++im) {
#pragma unroll
        for (int r2 = 0; r2 < 4; ++r2) {
            int row = m0 + im * 64 + (ty << 2) + r2;
#pragma unroll
            for (int in2 = 0; in2 < 2; ++in2) {
                int col = n0 + in2 * 64 + (tx << 2);
                float4 v;
                v.x = acc[im][in2][r2][0];
                v.y = acc[im][in2][r2][1];
                v.z = acc[im][in2][r2][2];
                v.w = acc[im][in2][r2][3];
                float4 bb = *(const float4*)&bias[col];
                v.x += bb.x; v.y += bb.y; v.z += bb.z; v.w += bb.w;
                if (MODE == 1) {
                    v.x = gelu_exact(v.x); v.y = gelu_exact(v.y);
                    v.z = gelu_exact(v.z); v.w = gelu_exact(v.w);
                }
                if (MODE == 2) {
                    float4 rr = *(const float4*)&res[(long)row * N + col];
                    v.x += rr.x; v.y += rr.y; v.z += rr.z; v.w += rr.w;
                }
                *(float4*)&Cm[(long)row * N + col] = v;
            }
        }
    }
}

// ---------------------------------------------------------------------------
// Encoder conv as implicit-im2row GEMM: M=BT, N=H, K=3584 (kap = tap*512 + i)
// A[m][kap] = x[b][t + tap - 3][i] (zero-padded in t); C = A@ewt + enc_b
// ---------------------------------------------------------------------------
__global__ __launch_bounds__(256) void k_gemm_enc(
    const float* __restrict__ X, const float* __restrict__ Bm,
    const float* __restrict__ bias, float* __restrict__ Cm) {
    __shared__ float As[16][132];
    __shared__ float Bs[16][136];
    const int tid = threadIdx.x;
    const int tx = tid & 15, ty = tid >> 4;
    const int m0 = blockIdx.y << 7, n0 = blockIdx.x << 7;
    const int arow = tid >> 2;
    const int akq = (tid & 3) << 2;
    const int brow = tid >> 4;
    const int bnq = (tid & 15) << 2;
    const int bq = (m0 + arow) >> 11;       // whole 128-row tile is in one batch
    const int t0 = (m0 + arow) & 2047;
    float acc[2][2][4][4] = {};
    const float* Xb = X + (long)bq * T_ * DIN;
    const float* Bp = Bm + (long)brow * H_ + n0 + bnq;

    for (int k0 = 0; k0 < 3584; k0 += 16) {
        int tap = k0 >> 9;
        int ioff = (k0 & 511) + akq;
        int ta = t0 + tap - 3;
        int tb = ta + 64;
        float4 a0 = make_float4(0.f, 0.f, 0.f, 0.f);
        float4 a1 = make_float4(0.f, 0.f, 0.f, 0.f);
        if ((unsigned)ta < (unsigned)T_) a0 = *(const float4*)&Xb[(long)ta * DIN + ioff];
        if ((unsigned)tb < (unsigned)T_) a1 = *(const float4*)&Xb[(long)tb * DIN + ioff];
        float4 b0 = *(const float4*)(Bp + (long)k0 * H_);
        float4 b1 = *(const float4*)(Bp + (long)k0 * H_ + 64);
        __syncthreads();
        As[akq + 0][arow] = a0.x;  As[akq + 1][arow] = a0.y;
        As[akq + 2][arow] = a0.z;  As[akq + 3][arow] = a0.w;
        As[akq + 0][arow + 64] = a1.x;  As[akq + 1][arow + 64] = a1.y;
        As[akq + 2][arow + 64] = a1.z;  As[akq + 3][arow + 64] = a1.w;
        *(float4*)&Bs[brow][bnq] = b0;
        *(float4*)&Bs[brow][bnq + 64] = b1;
        __syncthreads();
#pragma unroll
        for (int k = 0; k < 16; ++k) {
            float4 av0 = *(const float4*)&As[k][ty << 2];
            float4 av1 = *(const float4*)&As[k][(ty << 2) + 64];
            float4 bv0 = *(const float4*)&Bs[k][tx << 2];
            float4 bv1 = *(const float4*)&Bs[k][(tx << 2) + 64];
            float a_[8] = {av0.x, av0.y, av0.z, av0.w, av1.x, av1.y, av1.z, av1.w};
            float b_[8] = {bv0.x, bv0.y, bv0.z, bv0.w, bv1.x, bv1.y, bv1.z, bv1.w};
#pragma unroll
            for (int im = 0; im < 2; ++im)
#pragma unroll
                for (int r2 = 0; r2 < 4; ++r2)
#pragma unroll
                    for (int in2 = 0; in2 < 2; ++in2)
#pragma unroll
                        for (int c2 = 0; c2 < 4; ++c2)
                            acc[im][in2][r2][c2] =
                                fmaf(a_[im * 4 + r2], b_[in2 * 4 + c2], acc[im][in2][r2][c2]);
        }
    }

#pragma unroll
    for (int im = 0; im < 2; ++im) {
#pragma unroll
        for (int r2 = 0; r2 < 4; ++r2) {
            int row = m0 + im * 64 + (ty << 2) + r2;
#pragma unroll
            for (int in2 = 0; in2 < 2; ++in2) {
                int col = n0 + in2 * 64 + (tx << 2);
                float4 v;
                v.x = acc[im][in2][r2][0] + bias[col + 0];
                v.y = acc[im][in2][r2][1] + bias[col + 1];
                v.z = acc[im][in2][r2][2] + bias[col + 2];
                v.w = acc[im][in2][r2][3] + bias[col + 3];
                *(float4*)&Cm[(long)row * H_ + col] = v;
            }
        }
    }
}

// ---------------------------------------------------------------------------
// Fused out-conv (pointwise, C=8) + nearest-embedding argmin over K=8192
// 16 rows per block, 256 threads: 16 slices of the codebook per row.
// Embeddings staged in LDS in 8 chunks of 1024, 516-float padded groups
// (group stride % 32 == 4) so slice reads are bank-conflict-free.
// ---------------------------------------------------------------------------
__global__ __launch_bounds__(256) void k_outconv_argmin(
    const float* __restrict__ h, const float* __restrict__ ow,
    const float* __restrict__ ob, const float* __restrict__ emb,
    int* __restrict__ outIdx) {
    __shared__ float hs[16][H_ + 1];   // 24.6 KB
    __shared__ float zs[16][C_];       // 0.5 KB
    __shared__ float es[16 * 516];     // 33.0 KB (16 groups of 64 codes, padded)
    __shared__ float rb[16][16];
    __shared__ int ri[16][16];
    const int tid = threadIdx.x;
    const int row0 = blockIdx.x << 4;

    // stage 16 h-rows
    for (int i = tid; i < 16 * (H_ / 4); i += 256) {
        int r = i / 96;
        int c4 = (i % 96) << 2;
        float4 v = *(const float4*)&h[((long)(row0 + r)) * H_ + c4];
        hs[r][c4] = v.x; hs[r][c4 + 1] = v.y; hs[r][c4 + 2] = v.z; hs[r][c4 + 3] = v.w;
    }
    __syncthreads();

    // z[r][c] = h_row . out_w[c] + out_b[c]
    if (tid < 128) {
        int r = tid & 15, c = tid >> 4;
        float acc = ob[c];
        const float* wc = ow + c * H_;
        for (int j = 0; j < H_; ++j) acc = fmaf(hs[r][j], wc[j], acc);
        zs[r][c] = acc;
    }
    __syncthreads();

    const int r = tid & 15;
    const int sl = tid >> 4;
    float z0 = zs[r][0], z1 = zs[r][1], z2 = zs[r][2], z3 = zs[r][3];
    float z4 = zs[r][4], z5 = zs[r][5], z6 = zs[r][6], z7 = zs[r][7];
    float best = 3.4e38f;
    int bi = 0;

    for (int ch = 0; ch < 8; ++ch) {
        __syncthreads();
        for (int i = tid; i < 2048; i += 256) {
            int e = i >> 1;
            int half = (i & 1) << 2;
            float4 src = *(const float4*)&emb[(((long)(ch << 10)) + e) * C_ + half];
            *(float4*)&es[(e >> 6) * 516 + ((e & 63) << 3) + half] = src;
        }
        __syncthreads();
        const float* ep = es + sl * 516;   // slice sl == group sl
        int gbase = (ch << 10) + (sl << 6);
#pragma unroll 4
        for (int j = 0; j < 64; ++j) {
            float4 e0 = *(const float4*)(ep + (j << 3));
            float4 e1 = *(const float4*)(ep + (j << 3) + 4);
            float t, d;
            t = e0.x - z0; d = t * t;
            t = e0.y - z1; d = fmaf(t, t, d);
            t = e0.z - z2; d = fmaf(t, t, d);
            t = e0.w - z3; d = fmaf(t, t, d);
            t = e1.x - z4; d = fmaf(t, t, d);
            t = e1.y - z5; d = fmaf(t, t, d);
            t = e1.z - z6; d = fmaf(t, t, d);
            t = e1.w - z7; d = fmaf(t, t, d);
            if (d < best) { best = d; bi = gbase + j; }   // strict < keeps first index
        }
    }
    rb[r][sl] = best;
    ri[r][sl] = bi;
    __syncthreads();
    if (sl == 0) {
        float bb = rb[r][0];
        int bbi = ri[r][0];
#pragma unroll
        for (int s2 = 1; s2 < 16; ++s2) {
            float v = rb[r][s2];
            int i2 = ri[r][s2];
            if (v < bb || (v == bb && i2 < bbi)) { bb = v; bbi = i2; }
        }
        outIdx[row0 + r] = bbi;
    }
}

// ---------------------------------------------------------------------------
// host launcher
// ---------------------------------------------------------------------------
extern "C" void kernel_launch(void* const* d_in, const int* in_sizes, int n_in,
                              void* d_out, int out_size, void* d_ws, size_t ws_size,
                              hipStream_t stream) {
    const float* x        = (const float*)d_in[0];
    const float* enc_w    = (const float*)d_in[1];
    const float* enc_b    = (const float*)d_in[2];
    const float* enc_ln_g = (const float*)d_in[3];
    const float* enc_ln_b = (const float*)d_in[4];
    const float* blk_dw_w = (const float*)d_in[5];
    const float* blk_dw_b = (const float*)d_in[6];
    const float* blk_ln_g = (const float*)d_in[7];
    const float* blk_ln_b = (const float*)d_in[8];
    const float* blk_w1   = (const float*)d_in[9];
    const float* blk_b1   = (const float*)d_in[10];
    const float* blk_w2   = (const float*)d_in[11];
    const float* blk_b2   = (const float*)d_in[12];
    const float* out_w    = (const float*)d_in[13];
    const float* out_b    = (const float*)d_in[14];
    const float* emb      = (const float*)d_in[15];
    int* out = (int*)d_out;

    float* ws  = (float*)d_ws;
    float* h   = ws;                   // BT*H        =  6291456 f
    float* tmp = h + 6291456;          // BT*H        =  6291456 f
    float* ht4 = tmp + 6291456;        // BT*4H       = 25165824 f
    float* ewt = ht4 + 25165824;       // 3584*H      =  1376256 f
    float* w1t = ewt + 1376256;        // 6*H*4H      =  3538944 f
    float* w2t = w1t + 3538944;        // 6*4H*H      =  3538944 f  (total ~185 MB)

    // weight transposes
    k_transpose_encw<<<(3584 * H_ + 255) / 256, 256, 0, stream>>>(enc_w, ewt);
    k_transpose_b<<<dim3((H4_ * H_ + 255) / 256, 6), 256, 0, stream>>>(blk_w1, w1t, H4_, H_);
    k_transpose_b<<<dim3((H4_ * H_ + 255) / 256, 6), 256, 0, stream>>>(blk_w2, w2t, H_, H4_);

    // encoder conv (+bias) then LN
    k_gemm_enc<<<dim3(3, 128), 256, 0, stream>>>(x, ewt, enc_b, tmp);
    k_ln<<<BT_, 64, 0, stream>>>(tmp, h, enc_ln_g, enc_ln_b);

    for (int i = 0; i < 6; ++i) {
        k_dwconv_ln<<<BT_, 64, 0, stream>>>(h, tmp, blk_dw_w + i * H_ * 7,
                                            blk_dw_b + i * H_, blk_ln_g + i * H_,
                                            blk_ln_b + i * H_);
        // ht4 = gelu(tmp @ w1t + b1)
        k_gemm<1><<<dim3(12, 128), 256, 0, stream>>>(tmp, w1t + (long)i * H_ * H4_,
                                                     blk_b1 + i * H4_, nullptr, ht4,
                                                     H4_, H_);
        // h = ht4 @ w2t + b2 + h  (residual, in-place safe: 1 thread per element)
        k_gemm<2><<<dim3(3, 128), 256, 0, stream>>>(ht4, w2t + (long)i * H_ * H4_,
                                                    blk_b2 + i * H_, h, h, H_, H4_);
    }

    k_outconv_argmin<<<BT_ / 16, 256, 0, stream>>>(h, out_w, out_b, emb, out);
}